// Round 4
// baseline (626.295 us; speedup 1.0000x reference)
//
#include <hip/hip_runtime.h>
#include <math.h>

// GIN: agg commutes with first linear -> z = x@w1 precomputed.
// All inter-kernel node tensors (z, h) stored as bf16 (halves gather
// traffic + L2 footprint); accumulation fp32. Weights staged in LDS as
// bf16 (decode = shift<<16) -> agg LDS 37KB -> 4 blocks/CU.

#define NNODES 100000
#define NEDGES 1600000
#define NGRAPHS 512
#define NB 782     // ceil(100000/128)
#define BCAP 2432  // mean 2048, sd 45 -> +8.5 sigma
#define CHUNK 8192
#define NCHUNKS 196  // ceil(1600000/8192)

typedef unsigned short u16;

__device__ __forceinline__ u16 f2b(float f) {
  union {
    float f;
    unsigned u;
  } v;
  v.f = f;
  unsigned r = v.u + 0x7FFF + ((v.u >> 16) & 1);  // RN-even
  return (u16)(r >> 16);
}
__device__ __forceinline__ float b2f(u16 h) {
  union {
    unsigned u;
    float f;
  } v;
  v.u = ((unsigned)h) << 16;
  return v.f;
}

// ---------------- bucket init ----------------

__global__ __launch_bounds__(256) void init_gcur(int* __restrict__ gcur) {
  int i = blockIdx.x * 256 + threadIdx.x;
  if (i < NB) gcur[i] = i * BCAP;
}

// ---------------- binned scatter ----------------

__global__ __launch_bounds__(512) void bin_kernel(const int* __restrict__ src,
                                                  const int* __restrict__ dst,
                                                  int* __restrict__ gcur,
                                                  int* __restrict__ st) {
  __shared__ int hist[NB];
  __shared__ int lofs[NB + 1];
  __shared__ int lcur[NB];
  __shared__ int gbase[NB];
  __shared__ int sd[1024];
  __shared__ int staged[CHUNK];
  __shared__ u16 stb[CHUNK];
  const int t = threadIdx.x;
  const int e0 = blockIdx.x * CHUNK;
  const int n = min(CHUNK, NEDGES - e0);

  for (int i = t; i < NB; i += 512) hist[i] = 0;
  __syncthreads();

  int pk[16];
  int bk[16];
#pragma unroll
  for (int k = 0; k < 16; ++k) {
    int i = t + k * 512;
    if (i < n) {
      int s = src[e0 + i];
      int d = dst[e0 + i];
      int b = d >> 7;
      pk[k] = (s << 7) | (d & 127);
      bk[k] = b;
      atomicAdd(&hist[b], 1);
    } else {
      bk[k] = -1;
    }
  }
  __syncthreads();

  // inclusive scan of hist (782) via 2 elems/thread Hillis-Steele
  sd[t] = (t < NB) ? hist[t] : 0;
  sd[t + 512] = (t + 512 < NB) ? hist[t + 512] : 0;
  __syncthreads();
  for (int off = 1; off < 1024; off <<= 1) {
    int v0 = (t >= off) ? sd[t - off] : 0;
    int v1 = (t + 512 >= off) ? sd[t + 512 - off] : 0;
    __syncthreads();
    sd[t] += v0;
    sd[t + 512] += v1;
    __syncthreads();
  }
  if (t == 0) lofs[0] = 0;
  for (int i = t; i < NB; i += 512) {
    int inc = sd[i];
    int c = hist[i];
    lofs[i + 1] = inc;
    lcur[i] = inc - c;  // exclusive
    gbase[i] = c ? atomicAdd(&gcur[i], c) : 0;
  }
  __syncthreads();

#pragma unroll
  for (int k = 0; k < 16; ++k) {
    if (bk[k] >= 0) {
      int r = atomicAdd(&lcur[bk[k]], 1);
      staged[r] = pk[k];
      stb[r] = (u16)bk[k];
    }
  }
  __syncthreads();

  // copy out: bucket id read directly (no binary search)
  for (int i = t; i < n; i += 512) {
    int b = stb[i];
    st[gbase[b] + (i - lofs[b])] = staged[i];
  }
}

// ---------------- GEMM: z = x(Nx128) @ w1(128x64), z bf16 ----------------

__global__ __launch_bounds__(512) void gemm128_kernel(
    const float* __restrict__ x, const float* __restrict__ w1,
    u16* __restrict__ z) {
  __shared__ u16 w1h[128 * 64];       // 16 KB
  __shared__ float rows[8][128 * 4];  // 16 KB
  int tid = threadIdx.x;
  for (int i = tid; i < 128 * 64; i += 512) w1h[i] = f2b(w1[i]);
  __syncthreads();
  const int lane = tid & 63;
  const int wv = tid >> 6;
  float* myrows = rows[wv];
  const int n0 = (blockIdx.x * 8 + wv) * 4;

  float lo[4], hi[4];
#pragma unroll
  for (int j = 0; j < 4; ++j) {
    lo[j] = x[(size_t)(n0 + j) * 128 + lane];
    hi[j] = x[(size_t)(n0 + j) * 128 + 64 + lane];
  }
  *(float4*)&myrows[lane * 4] = make_float4(lo[0], lo[1], lo[2], lo[3]);
  *(float4*)&myrows[(64 + lane) * 4] = make_float4(hi[0], hi[1], hi[2], hi[3]);
  __asm__ volatile("s_waitcnt lgkmcnt(0)" ::: "memory");

  float acc[4] = {0.f, 0.f, 0.f, 0.f};
#pragma unroll 8
  for (int k = 0; k < 128; ++k) {
    float4 r = *(const float4*)&myrows[k * 4];
    float w = b2f(w1h[k * 64 + lane]);
    acc[0] += r.x * w;
    acc[1] += r.y * w;
    acc[2] += r.z * w;
    acc[3] += r.w * w;
  }
#pragma unroll
  for (int j = 0; j < 4; ++j) z[(size_t)(n0 + j) * 64 + lane] = f2b(acc[j]);
}

// ---------------- agg: 1 bucket (128 nodes) per block ----------------

template <bool HAS_NEXT>
__global__ __launch_bounds__(512) void agg_kernel(
    const u16* __restrict__ zin, const float* __restrict__ b1,
    const float* __restrict__ w2, const float* __restrict__ b2,
    const float* __restrict__ w1n, const float* __restrict__ eps, int li,
    const int* __restrict__ gcur, const int* __restrict__ st,
    u16* __restrict__ hout, u16* __restrict__ zn) {
  __shared__ u16 w2h[64 * 64];  // 8 KB
  __shared__ u16 w1nh[HAS_NEXT ? 64 * 64 : 2];
  __shared__ float b1s[64], b2s[64];
  __shared__ float rows[8][256];  // 8 KB
  __shared__ int lcol[BCAP];      // 9.5 KB
  __shared__ int lhist[128];
  __shared__ int lofs[129];
  __shared__ int lcur[128];
  __shared__ int ssc[128];
  const int tid = threadIdx.x;
  const int b = blockIdx.x;
  const int base = b << 7;
  const int ofs = b * BCAP;
  const int cnt = min(gcur[b] - ofs, BCAP);

  for (int i = tid; i < 64 * 64; i += 512) {
    w2h[i] = f2b(w2[i]);
    if (HAS_NEXT) w1nh[i] = f2b(w1n[i]);
  }
  if (tid < 64) {
    b1s[tid] = b1[tid];
    b2s[tid] = b2[tid];
  }
  if (tid < 128) lhist[tid] = 0;
  __syncthreads();

  for (int i = tid; i < cnt; i += 512) {
    atomicAdd(&lhist[st[ofs + i] & 127], 1);
  }
  __syncthreads();
  if (tid < 128) ssc[tid] = lhist[tid];
  __syncthreads();
  for (int off = 1; off < 128; off <<= 1) {
    int v = (tid < 128 && tid >= off) ? ssc[tid - off] : 0;
    __syncthreads();
    if (tid < 128) ssc[tid] += v;
    __syncthreads();
  }
  if (tid < 128) {
    lofs[tid + 1] = ssc[tid];
    lcur[tid] = ssc[tid] - lhist[tid];
  }
  if (tid == 0) lofs[0] = 0;
  __syncthreads();
  for (int i = tid; i < cnt; i += 512) {
    int p = st[ofs + i];
    int r = atomicAdd(&lcur[p & 127], 1);
    lcol[r] = p >> 7;
  }
  __syncthreads();

  const float e1 = 1.0f + eps[li];
  const int lane = tid & 63;
  const int wv = tid >> 6;
  float* myrows = rows[wv];

#pragma unroll 1
  for (int pass = 0; pass < 4; ++pass) {
    const int ln0 = pass * 32 + wv * 4;
    float a[4];
#pragma unroll
    for (int j = 0; j < 4; ++j) {
      int ln = ln0 + j;
      int nn = base + ln;
      int rs = lofs[ln], re = lofs[ln + 1];
      float s0 = 0.f, s1 = 0.f, s2 = 0.f, s3 = 0.f;
      int e = rs;
      for (; e + 4 <= re; e += 4) {
        int c0 = lcol[e], c1 = lcol[e + 1], c2 = lcol[e + 2], c3 = lcol[e + 3];
        s0 += b2f(zin[(size_t)c0 * 64 + lane]);
        s1 += b2f(zin[(size_t)c1 * 64 + lane]);
        s2 += b2f(zin[(size_t)c2 * 64 + lane]);
        s3 += b2f(zin[(size_t)c3 * 64 + lane]);
      }
      for (; e < re; ++e) s0 += b2f(zin[(size_t)lcol[e] * 64 + lane]);
      float self = (nn < NNODES) ? b2f(zin[(size_t)nn * 64 + lane]) : 0.f;
      a[j] = (s0 + s1) + (s2 + s3) + e1 * self;
    }
    float bb = b1s[lane];
#pragma unroll
    for (int j = 0; j < 4; ++j) a[j] = fmaxf(a[j] + bb, 0.f);
    *(float4*)&myrows[lane * 4] = make_float4(a[0], a[1], a[2], a[3]);
    __asm__ volatile("s_waitcnt lgkmcnt(0)" ::: "memory");

    float o[4];
    float b2v = b2s[lane];
#pragma unroll
    for (int j = 0; j < 4; ++j) o[j] = b2v;
#pragma unroll 8
    for (int k = 0; k < 64; ++k) {
      float4 r = *(const float4*)&myrows[k * 4];
      float w = b2f(w2h[k * 64 + lane]);
      o[0] += r.x * w;
      o[1] += r.y * w;
      o[2] += r.z * w;
      o[3] += r.w * w;
    }
#pragma unroll
    for (int j = 0; j < 4; ++j) {
      o[j] = fmaxf(o[j], 0.f);
      int nn = base + ln0 + j;
      if (nn < NNODES) hout[(size_t)nn * 64 + lane] = f2b(o[j]);
    }

    if (HAS_NEXT) {
      __asm__ volatile("s_waitcnt lgkmcnt(0)" ::: "memory");
      *(float4*)&myrows[lane * 4] = make_float4(o[0], o[1], o[2], o[3]);
      __asm__ volatile("s_waitcnt lgkmcnt(0)" ::: "memory");
      float q[4] = {0.f, 0.f, 0.f, 0.f};
#pragma unroll 8
      for (int k = 0; k < 64; ++k) {
        float4 r = *(const float4*)&myrows[k * 4];
        float w = b2f(w1nh[k * 64 + lane]);
        q[0] += r.x * w;
        q[1] += r.y * w;
        q[2] += r.z * w;
        q[3] += r.w * w;
      }
#pragma unroll
      for (int j = 0; j < 4; ++j) {
        int nn = base + ln0 + j;
        if (nn < NNODES) zn[(size_t)nn * 64 + lane] = f2b(q[j]);
      }
    }
    __asm__ volatile("s_waitcnt lgkmcnt(0)" ::: "memory");
  }
}

// ---------------- Per-graph pooling (batch sorted, h bf16) ----------------

__device__ __forceinline__ int lower_bound(const int* __restrict__ a, int n,
                                           int v) {
  int lo = 0, hi = n;
  while (lo < hi) {
    int m = (lo + hi) >> 1;
    if (a[m] < v)
      lo = m + 1;
    else
      hi = m;
  }
  return lo;
}

__global__ __launch_bounds__(256) void pool_kernel(const u16* __restrict__ h,
                                                   const int* __restrict__ batch,
                                                   float* __restrict__ g,
                                                   int li) {
  int gi = blockIdx.x;
  int tid = threadIdx.x;
  int sub = tid >> 6, f = tid & 63;
  int s = lower_bound(batch, NNODES, gi);
  int e = lower_bound(batch, NNODES, gi + 1);
  float sum = 0.f, mx = -3.0e38f;
  for (int n = s + sub; n < e; n += 4) {
    float v = b2f(h[(size_t)n * 64 + f]);
    sum += v;
    mx = fmaxf(mx, v);
  }
  __shared__ float ssum[4][64];
  __shared__ float smax[4][64];
  ssum[sub][f] = sum;
  smax[sub][f] = mx;
  __syncthreads();
  if (tid < 64) {
    float S = ssum[0][f] + ssum[1][f] + ssum[2][f] + ssum[3][f];
    float M = fmaxf(fmaxf(smax[0][f], smax[1][f]), fmaxf(smax[2][f], smax[3][f]));
    int cnt = e - s;
    float mean = S / fmaxf((float)cnt, 1.0f);
    int base = gi * 576 + li * 64 + f;
    g[base] = mean;
    g[base + 192] = M;
    g[base + 384] = S;
  }
}

// ---------------- Head ----------------

__global__ __launch_bounds__(256) void head_kernel(
    const float* __restrict__ g, const float* __restrict__ fc1w,
    const float* __restrict__ fc1b, const float* __restrict__ fc2w,
    const float* __restrict__ fc2b, float* __restrict__ out) {
  __shared__ float gs[4 * 576];
  int tid = threadIdx.x;
  int g0 = blockIdx.x * 4;
  for (int i = tid; i < 4 * 576; i += 256) gs[i] = g[g0 * 576 + i];
  __syncthreads();
  int wv = tid >> 6, lane = tid & 63;
  int gi = g0 + wv;
  const float* grow = &gs[wv * 576];
  float acc = fc1b[lane];
#pragma unroll 8
  for (int k = 0; k < 576; ++k) acc += grow[k] * fc1w[k * 64 + lane];
  acc = fmaxf(acc, 0.f);
  float p0 = acc * fc2w[lane * 2 + 0];
  float p1 = acc * fc2w[lane * 2 + 1];
  for (int off = 32; off; off >>= 1) {
    p0 += __shfl_down(p0, off);
    p1 += __shfl_down(p1, off);
  }
  if (lane == 0) {
    out[gi * 2 + 0] = 1.f / (1.f + __expf(-(p0 + fc2b[0])));
    out[gi * 2 + 1] = 1.f / (1.f + __expf(-(p1 + fc2b[1])));
  }
}

// ---------------- launch ----------------

extern "C" void kernel_launch(void* const* d_in, const int* in_sizes, int n_in,
                              void* d_out, int out_size, void* d_ws,
                              size_t ws_size, hipStream_t stream) {
  const float* x = (const float*)d_in[0];
  const int* ei = (const int*)d_in[1];
  const int* src = ei;
  const int* dst = ei + NEDGES;
  const int* batch = (const int*)d_in[2];
  const float* lw1[3] = {(const float*)d_in[3], (const float*)d_in[7],
                         (const float*)d_in[11]};
  const float* lb1[3] = {(const float*)d_in[4], (const float*)d_in[8],
                         (const float*)d_in[12]};
  const float* lw2[3] = {(const float*)d_in[5], (const float*)d_in[9],
                         (const float*)d_in[13]};
  const float* lb2[3] = {(const float*)d_in[6], (const float*)d_in[10],
                         (const float*)d_in[14]};
  const float* eps = (const float*)d_in[15];
  const float* fc1w = (const float*)d_in[16];
  const float* fc1b = (const float*)d_in[17];
  const float* fc2w = (const float*)d_in[18];
  const float* fc2b = (const float*)d_in[19];
  float* out = (float*)d_out;

  char* p = (char*)d_ws;
  auto carve = [&](size_t bytes) {
    void* r = (void*)p;
    p += (bytes + 1023) & ~(size_t)1023;
    return r;
  };
  int* gcur = (int*)carve((NB + 4) * 4);
  int* st = (int*)carve((size_t)NB * BCAP * 4);
  u16* zA = (u16*)carve((size_t)NNODES * 64 * 2);
  u16* zB = (u16*)carve((size_t)NNODES * 64 * 2);
  u16* hA = (u16*)carve((size_t)NNODES * 64 * 2);
  float* g = (float*)carve((size_t)NGRAPHS * 576 * 4);

  init_gcur<<<(NB + 255) / 256, 256, 0, stream>>>(gcur);
  bin_kernel<<<NCHUNKS, 512, 0, stream>>>(src, dst, gcur, st);

  gemm128_kernel<<<3125, 512, 0, stream>>>(x, lw1[0], zA);

  agg_kernel<true><<<NB, 512, 0, stream>>>(zA, lb1[0], lw2[0], lb2[0], lw1[1],
                                           eps, 0, gcur, st, hA, zB);
  pool_kernel<<<NGRAPHS, 256, 0, stream>>>(hA, batch, g, 0);

  agg_kernel<true><<<NB, 512, 0, stream>>>(zB, lb1[1], lw2[1], lb2[1], lw1[2],
                                           eps, 1, gcur, st, hA, zA);
  pool_kernel<<<NGRAPHS, 256, 0, stream>>>(hA, batch, g, 1);

  agg_kernel<false><<<NB, 512, 0, stream>>>(zA, lb1[2], lw2[2], lb2[2],
                                            (const float*)nullptr, eps, 2, gcur,
                                            st, hA, (u16*)nullptr);
  pool_kernel<<<NGRAPHS, 256, 0, stream>>>(hA, batch, g, 2);

  head_kernel<<<NGRAPHS / 4, 256, 0, stream>>>(g, fc1w, fc1b, fc2w, fc2b, out);
}